// Round 2
// baseline (52.405 us; speedup 1.0000x reference)
//
#include <hip/hip_runtime.h>
#include <hip/hip_bf16.h>
#include <stdint.h>

#define NN 1024
#define EMBED 256
#define NHEAD 8
#define NHID 32
#define SLOPE 0.2f

// ---------------- zero the adjacency bitmask (avoids slow rocclr fill) -------
__global__ void k_zero(unsigned long long* __restrict__ adj) {
    adj[blockIdx.x * 256 + threadIdx.x] = 0ull;
}

// ---------------- edge -> adjacency bitmask (dedupes duplicates) -------------
__global__ void k_edges(const int* __restrict__ ei, unsigned long long* __restrict__ adj, int E) {
    int e = blockIdx.x * blockDim.x + threadIdx.x;
    if (e < E) {
        int r = ei[2 * e];      // destination i
        int c = ei[2 * e + 1];  // source j
        atomicOr(&adj[r * 16 + (c >> 6)], 1ull << (c & 63));
    }
}

// ---------------- g_l = h@W_l, g_r = h@W_r (selected by blockIdx.z) ----------
// BM=64, BN=64, BK=16, 256 threads, 4x4 micro-tile per thread.
__global__ __launch_bounds__(256) void k_gemm(const float* __restrict__ h,
                                              const float* __restrict__ Wl,
                                              const float* __restrict__ Wr,
                                              float* __restrict__ gl,
                                              float* __restrict__ gr) {
    const float* W = blockIdx.z ? Wr : Wl;
    float* out = blockIdx.z ? gr : gl;
    const int bm = blockIdx.y * 64;
    const int bn = blockIdx.x * 64;
    const int t = threadIdx.x;
    const int tx = t & 15;       // 0..15 -> 4 cols each
    const int ty = t >> 4;       // 0..15 -> 4 rows each

    __shared__ float As[16][65];   // [k][m]
    __shared__ float Bs[16][65];   // [k][n]

    float acc[4][4];
#pragma unroll
    for (int i = 0; i < 4; ++i)
#pragma unroll
        for (int j = 0; j < 4; ++j) acc[i][j] = 0.f;

    for (int k0 = 0; k0 < EMBED; k0 += 16) {
        // A tile: 64 rows x 16 k. thread loads float4: row = t/4, k = (t%4)*4
        {
            int r = t >> 2;
            int c = (t & 3) << 2;
            float4 v = *reinterpret_cast<const float4*>(&h[(bm + r) * EMBED + k0 + c]);
            As[c + 0][r] = v.x;
            As[c + 1][r] = v.y;
            As[c + 2][r] = v.z;
            As[c + 3][r] = v.w;
        }
        // B tile: 16 k x 64 cols. thread loads float4: k = t/16, col = (t%16)*4
        {
            int r = t >> 4;
            int c = (t & 15) << 2;
            float4 v = *reinterpret_cast<const float4*>(&W[(k0 + r) * EMBED + bn + c]);
            Bs[r][c + 0] = v.x;
            Bs[r][c + 1] = v.y;
            Bs[r][c + 2] = v.z;
            Bs[r][c + 3] = v.w;
        }
        __syncthreads();
#pragma unroll
        for (int kk = 0; kk < 16; ++kk) {
            float a[4], b[4];
#pragma unroll
            for (int i = 0; i < 4; ++i) a[i] = As[kk][ty * 4 + i];
#pragma unroll
            for (int j = 0; j < 4; ++j) b[j] = Bs[kk][tx * 4 + j];
#pragma unroll
            for (int i = 0; i < 4; ++i)
#pragma unroll
                for (int j = 0; j < 4; ++j) acc[i][j] += a[i] * b[j];
        }
        __syncthreads();
    }

#pragma unroll
    for (int i = 0; i < 4; ++i) {
        float4 v = make_float4(acc[i][0], acc[i][1], acc[i][2], acc[i][3]);
        *reinterpret_cast<float4*>(&out[(bm + ty * 4 + i) * EMBED + bn + tx * 4]) = v;
    }
}

// ---------------- per-destination-row sparse softmax + aggregate -------------
// One block (256 threads) per destination row i. Thread t owns output feature
// f = t  (head h = t/32, dim d = t%32). All threads walk the same (uniform)
// edge list from the adjacency bits; scores reduce within each 32-lane group.
__global__ __launch_bounds__(256) void k_attn(const float* __restrict__ gl,
                                              const float* __restrict__ gr,
                                              const unsigned long long* __restrict__ adj,
                                              const float* __restrict__ attn_w,
                                              float* __restrict__ out) {
    const int i = blockIdx.x;
    const int t = threadIdx.x;

    const float grv = gr[i * EMBED + t];
    const float aw = attn_w[t & 31];

    float m = -INFINITY;
    float s = 0.f;
    float acc = 0.f;

    for (int w = 0; w < 16; ++w) {
        unsigned long long bits = adj[i * 16 + w];
        while (bits) {
            int b = __builtin_ctzll(bits);
            bits &= bits - 1;
            int j = w * 64 + b;
            float glv = gl[j * EMBED + t];
            float x = glv + grv;
            float p = (x > 0.f ? x : SLOPE * x) * aw;
            // sum over d (32 lanes of this head's group)
            p += __shfl_xor(p, 1);
            p += __shfl_xor(p, 2);
            p += __shfl_xor(p, 4);
            p += __shfl_xor(p, 8);
            p += __shfl_xor(p, 16);
            // online softmax update
            float mn = fmaxf(m, p);
            float sc = __expf(m - mn);
            float ev = __expf(p - mn);
            s = s * sc + ev;
            acc = acc * sc + ev * glv;
            m = mn;
        }
    }
    out[i * EMBED + t] = acc / s;
}

extern "C" void kernel_launch(void* const* d_in, const int* in_sizes, int n_in,
                              void* d_out, int out_size, void* d_ws, size_t ws_size,
                              hipStream_t stream) {
    const float* h  = (const float*)d_in[0];
    const int*   ei = (const int*)d_in[1];
    const float* Wl = (const float*)d_in[2];
    const float* Wr = (const float*)d_in[3];
    const float* aw = (const float*)d_in[4];
    float* out = (float*)d_out;
    const int E = in_sizes[1] / 2;

    unsigned long long* adj = (unsigned long long*)d_ws;                 // 128 KB
    float* gl = (float*)((char*)d_ws + 131072);                          // 1 MB
    float* gr = gl + NN * EMBED;                                         // 1 MB

    k_zero<<<NN * 16 / 256, 256, 0, stream>>>(adj);
    k_edges<<<(E + 255) / 256, 256, 0, stream>>>(ei, adj, E);
    dim3 gg(EMBED / 64, NN / 64, 2);
    k_gemm<<<gg, 256, 0, stream>>>(h, Wl, Wr, gl, gr);
    k_attn<<<NN, 256, 0, stream>>>(gl, gr, adj, aw, out);
}

// Round 3
// 51.921 us; speedup vs baseline: 1.0093x; 1.0093x over previous
//
#include <hip/hip_runtime.h>
#include <hip/hip_bf16.h>
#include <stdint.h>

#define NN 1024
#define EMBED 256
#define NHEAD 8
#define NHID 32
#define SLOPE 0.2f

// ---------------------------------------------------------------------------
// Kernel 1: fused prep.
//   blocks [0,128)  : gl = h@W_l, gr = h@W_r   (64x64 tiles, BK=16)
//   blocks [128,192): adjacency bitmask build. Block b owns 16 destination
//     rows; it streams the full edge list and sets bits in LDS (dedupes
//     duplicates via OR), then writes its 16*32 uint words to global.
//     No global zeroing pass and no global atomics needed.
// ---------------------------------------------------------------------------
__global__ __launch_bounds__(256) void k_prep(const float* __restrict__ h,
                                              const float* __restrict__ Wl,
                                              const float* __restrict__ Wr,
                                              const int* __restrict__ ei, int E,
                                              float* __restrict__ gl,
                                              float* __restrict__ gr,
                                              unsigned int* __restrict__ adj) {
    const int blk = blockIdx.x;
    const int t = threadIdx.x;

    if (blk < 128) {
        const int z  = blk & 1;
        const int bn = ((blk >> 1) & 3) * 64;
        const int bm = (blk >> 3) * 64;
        const float* W = z ? Wr : Wl;
        float* out = z ? gr : gl;
        const int tx = t & 15;
        const int ty = t >> 4;

        __shared__ float As[16][65];   // [k][m]
        __shared__ float Bs[16][65];   // [k][n]

        float acc[4][4];
#pragma unroll
        for (int i = 0; i < 4; ++i)
#pragma unroll
            for (int j = 0; j < 4; ++j) acc[i][j] = 0.f;

        for (int k0 = 0; k0 < EMBED; k0 += 16) {
            {
                int r = t >> 2;
                int c = (t & 3) << 2;
                float4 v = *reinterpret_cast<const float4*>(&h[(bm + r) * EMBED + k0 + c]);
                As[c + 0][r] = v.x; As[c + 1][r] = v.y;
                As[c + 2][r] = v.z; As[c + 3][r] = v.w;
            }
            {
                int r = t >> 4;
                int c = (t & 15) << 2;
                float4 v = *reinterpret_cast<const float4*>(&W[(k0 + r) * EMBED + bn + c]);
                Bs[r][c + 0] = v.x; Bs[r][c + 1] = v.y;
                Bs[r][c + 2] = v.z; Bs[r][c + 3] = v.w;
            }
            __syncthreads();
#pragma unroll
            for (int kk = 0; kk < 16; ++kk) {
                float a[4], b[4];
#pragma unroll
                for (int i = 0; i < 4; ++i) a[i] = As[kk][ty * 4 + i];
#pragma unroll
                for (int j = 0; j < 4; ++j) b[j] = Bs[kk][tx * 4 + j];
#pragma unroll
                for (int i = 0; i < 4; ++i)
#pragma unroll
                    for (int j = 0; j < 4; ++j) acc[i][j] += a[i] * b[j];
            }
            __syncthreads();
        }
#pragma unroll
        for (int i = 0; i < 4; ++i) {
            float4 v = make_float4(acc[i][0], acc[i][1], acc[i][2], acc[i][3]);
            *reinterpret_cast<float4*>(&out[(bm + ty * 4 + i) * EMBED + bn + tx * 4]) = v;
        }
    } else {
        // adjacency build for rows [lo, lo+16), 32 uint words per row
        const int lo = (blk - 128) * 16;
        __shared__ unsigned int lads[16 * 32];
        if (t < 512) lads[t] = 0u;          // 256 threads -> 2 stores each
        lads[t + (t < 256 ? 0 : 0)] = lads[t + (t < 256 ? 0 : 0)]; // no-op keep simple
        if (t < 512 - 256) lads[t + 256] = 0u;
        __syncthreads();
        for (int e = t; e < E; e += 256) {
            int2 rc = reinterpret_cast<const int2*>(ei)[e];
            int r = rc.x - lo;
            if ((unsigned)r < 16u) {
                atomicOr(&lads[r * 32 + (rc.y >> 5)], 1u << (rc.y & 31));
            }
        }
        __syncthreads();
        adj[lo * 32 + t] = lads[t];
        adj[lo * 32 + t + 256] = lads[t + 256];
    }
}

// ---------------------------------------------------------------------------
// Kernel 2: per-destination-row sparse softmax + aggregate.
// One block per row i; thread t owns feature f=t (head t/32, dim t%32).
// Wave 0 compacts the row's set bits into an LDS neighbor list
// (deterministic prefix-sum compaction), then all threads run a counted,
// one-deep-prefetched online-softmax loop.
// ---------------------------------------------------------------------------
__global__ __launch_bounds__(256) void k_attn(const float* __restrict__ gl,
                                              const float* __restrict__ gr,
                                              const unsigned int* __restrict__ adj,
                                              const float* __restrict__ attn_w,
                                              float* __restrict__ out) {
    const int i = blockIdx.x;
    const int t = threadIdx.x;

    __shared__ int nbr[NN];
    __shared__ int cnt_s;

    if (t < 64) {
        unsigned int w = (t < 32) ? adj[i * 32 + t] : 0u;
        int c = __popc(w);
        int pre = c;
#pragma unroll
        for (int d = 1; d < 64; d <<= 1) {
            int v = __shfl_up(pre, d);
            if (t >= d) pre += v;
        }
        int off = pre - c;          // exclusive prefix
        if (t == 63) cnt_s = pre;   // total
        while (w) {
            int b = __builtin_ctz(w);
            w &= w - 1;
            nbr[off++] = t * 32 + b;
        }
    }
    __syncthreads();

    const int cnt = cnt_s;
    const float grv = gr[i * EMBED + t];
    const float aw = attn_w[t & 31];

    float m = -INFINITY;
    float s = 0.f;
    float acc = 0.f;

    float gv = gl[nbr[0] * EMBED + t];
    for (int e = 0; e < cnt; ++e) {
        float glv = gv;
        if (e + 1 < cnt) gv = gl[nbr[e + 1] * EMBED + t];   // prefetch next row
        float x = glv + grv;
        float p = (x > 0.f ? x : SLOPE * x) * aw;
        p += __shfl_xor(p, 1);
        p += __shfl_xor(p, 2);
        p += __shfl_xor(p, 4);
        p += __shfl_xor(p, 8);
        p += __shfl_xor(p, 16);
        float mn = fmaxf(m, p);
        float sc = __expf(m - mn);
        float ev = __expf(p - mn);
        s = s * sc + ev;
        acc = acc * sc + ev * glv;
        m = mn;
    }
    out[i * EMBED + t] = acc / s;
}

extern "C" void kernel_launch(void* const* d_in, const int* in_sizes, int n_in,
                              void* d_out, int out_size, void* d_ws, size_t ws_size,
                              hipStream_t stream) {
    const float* h  = (const float*)d_in[0];
    const int*   ei = (const int*)d_in[1];
    const float* Wl = (const float*)d_in[2];
    const float* Wr = (const float*)d_in[3];
    const float* aw = (const float*)d_in[4];
    float* out = (float*)d_out;
    const int E = in_sizes[1] / 2;

    unsigned int* adj = (unsigned int*)d_ws;                 // 128 KB
    float* gl = (float*)((char*)d_ws + 131072);              // 1 MB
    float* gr = gl + NN * EMBED;                             // 1 MB

    k_prep<<<192, 256, 0, stream>>>(h, Wl, Wr, ei, E, gl, gr, adj);
    k_attn<<<NN, 256, 0, stream>>>(gl, gr, adj, aw, out);
}

// Round 4
// 36.413 us; speedup vs baseline: 1.4392x; 1.4259x over previous
//
#include <hip/hip_runtime.h>
#include <hip/hip_bf16.h>
#include <stdint.h>

#define NN 1024
#define EMBED 256
#define NHEAD 8
#define NHID 32
#define SLOPE 0.2f

// ---------------------------------------------------------------------------
// Kernel 1: fused prep. 256 blocks:
//   blocks [0,128)  : gl = h@W_l, gr = h@W_r (64x64 tiles, BK=16, reg-prefetch)
//   blocks [128,256): adjacency bitmask. Block owns 8 rows (256 LDS words),
//     streams edge list as int4 x4 per thread per iter (8 edges/thread/iter).
// ---------------------------------------------------------------------------
__global__ __launch_bounds__(256) void k_prep(const float* __restrict__ h,
                                              const float* __restrict__ Wl,
                                              const float* __restrict__ Wr,
                                              const int* __restrict__ ei, int E,
                                              float* __restrict__ gl,
                                              float* __restrict__ gr,
                                              unsigned int* __restrict__ adj) {
    const int blk = blockIdx.x;
    const int t = threadIdx.x;

    if (blk < 128) {
        const int z  = blk & 1;
        const int bn = ((blk >> 1) & 3) * 64;
        const int bm = (blk >> 3) * 64;
        const float* W = z ? Wr : Wl;
        float* out = z ? gr : gl;
        const int tx = t & 15;
        const int ty = t >> 4;

        __shared__ float As[16][65];   // [k][m]
        __shared__ float Bs[16][65];   // [k][n]

        const int ar = t >> 2, ac = (t & 3) << 2;    // A: row in tile, k
        const int br = t >> 4, bc = (t & 15) << 2;   // B: k, col in tile
        const float* Aptr = &h[(bm + ar) * EMBED + ac];
        const float* Bptr = &W[br * EMBED + bn + bc];

        float acc[4][4];
#pragma unroll
        for (int i = 0; i < 4; ++i)
#pragma unroll
            for (int j = 0; j < 4; ++j) acc[i][j] = 0.f;

        float4 a_reg = *reinterpret_cast<const float4*>(Aptr);
        float4 b_reg = *reinterpret_cast<const float4*>(Bptr);

        for (int k0 = 0; k0 < EMBED; k0 += 16) {
            As[ac + 0][ar] = a_reg.x; As[ac + 1][ar] = a_reg.y;
            As[ac + 2][ar] = a_reg.z; As[ac + 3][ar] = a_reg.w;
            Bs[br][bc + 0] = b_reg.x; Bs[br][bc + 1] = b_reg.y;
            Bs[br][bc + 2] = b_reg.z; Bs[br][bc + 3] = b_reg.w;
            __syncthreads();
            if (k0 + 16 < EMBED) {      // prefetch next K-tile into registers
                a_reg = *reinterpret_cast<const float4*>(Aptr + k0 + 16);
                b_reg = *reinterpret_cast<const float4*>(Bptr + (size_t)(k0 + 16) * EMBED);
            }
#pragma unroll
            for (int kk = 0; kk < 16; ++kk) {
                float a[4], b[4];
#pragma unroll
                for (int i = 0; i < 4; ++i) a[i] = As[kk][ty * 4 + i];
#pragma unroll
                for (int j = 0; j < 4; ++j) b[j] = Bs[kk][tx * 4 + j];
#pragma unroll
                for (int i = 0; i < 4; ++i)
#pragma unroll
                    for (int j = 0; j < 4; ++j) acc[i][j] += a[i] * b[j];
            }
            __syncthreads();
        }
#pragma unroll
        for (int i = 0; i < 4; ++i) {
            float4 v = make_float4(acc[i][0], acc[i][1], acc[i][2], acc[i][3]);
            *reinterpret_cast<float4*>(&out[(bm + ty * 4 + i) * EMBED + bn + tx * 4]) = v;
        }
    } else {
        // adjacency build for 8 rows [lo, lo+8): 256 uint words in LDS
        const int lo = (blk - 128) * 8;
        __shared__ unsigned int lads[256];
        lads[t] = 0u;
        __syncthreads();

        const int4* ei4 = reinterpret_cast<const int4*>(ei);  // 2 edges / int4
        const int nvec = E >> 1;
        int base = 0;
        for (; base + 1024 <= nvec; base += 1024) {
            int4 v0 = ei4[base + t];
            int4 v1 = ei4[base + t + 256];
            int4 v2 = ei4[base + t + 512];
            int4 v3 = ei4[base + t + 768];
#pragma unroll
            for (int u = 0; u < 4; ++u) {
                int4 v = (u == 0) ? v0 : (u == 1) ? v1 : (u == 2) ? v2 : v3;
                int r0 = v.x - lo;
                if ((unsigned)r0 < 8u)
                    atomicOr(&lads[r0 * 32 + ((unsigned)v.y >> 5)], 1u << (v.y & 31));
                int r1 = v.z - lo;
                if ((unsigned)r1 < 8u)
                    atomicOr(&lads[r1 * 32 + ((unsigned)v.w >> 5)], 1u << (v.w & 31));
            }
        }
        for (int idx = base + t; idx < nvec; idx += 256) {
            int4 v = ei4[idx];
            int r0 = v.x - lo;
            if ((unsigned)r0 < 8u)
                atomicOr(&lads[r0 * 32 + ((unsigned)v.y >> 5)], 1u << (v.y & 31));
            int r1 = v.z - lo;
            if ((unsigned)r1 < 8u)
                atomicOr(&lads[r1 * 32 + ((unsigned)v.w >> 5)], 1u << (v.w & 31));
        }
        __syncthreads();
        adj[lo * 32 + t] = lads[t];
    }
}

// ---------------------------------------------------------------------------
// Kernel 2: per-destination-row sparse softmax + aggregate.
// One block per row i; thread t owns feature f=t (head t/32, dim t%32).
// Wave 0 compacts set bits into an LDS neighbor list, then all threads run
// an unroll-4, one-group-ahead-prefetched online-softmax loop.
// ---------------------------------------------------------------------------
__global__ __launch_bounds__(256) void k_attn(const float* __restrict__ gl,
                                              const float* __restrict__ gr,
                                              const unsigned int* __restrict__ adj,
                                              const float* __restrict__ attn_w,
                                              float* __restrict__ out) {
    const int i = blockIdx.x;
    const int t = threadIdx.x;

    __shared__ int nbr[NN];
    __shared__ int cnt_s;

    if (t < 64) {
        unsigned int w = (t < 32) ? adj[i * 32 + t] : 0u;
        int c = __popc(w);
        int pre = c;
#pragma unroll
        for (int d = 1; d < 64; d <<= 1) {
            int v = __shfl_up(pre, d);
            if (t >= d) pre += v;
        }
        int off = pre - c;          // exclusive prefix
        if (t == 63) cnt_s = pre;   // total count
        while (w) {
            int b = __builtin_ctz(w);
            w &= w - 1;
            nbr[off++] = t * 32 + b;
        }
    }
    __syncthreads();

    const int cnt = cnt_s;
    const float grv = gr[i * EMBED + t];
    const float aw = attn_w[t & 31];

    float m = -3e38f;
    float s = 0.f;
    float acc = 0.f;

    // prefetch group 0
    float g[4];
#pragma unroll
    for (int u = 0; u < 4; ++u) {
        int e = u < cnt ? u : 0;
        g[u] = gl[nbr[e] * EMBED + t];
    }

    for (int e0 = 0; e0 < cnt; e0 += 4) {
        float cg[4];
#pragma unroll
        for (int u = 0; u < 4; ++u) cg[u] = g[u];
        // prefetch next group (independent of the update chain below)
#pragma unroll
        for (int u = 0; u < 4; ++u) {
            int e = e0 + 4 + u;
            e = e < cnt ? e : 0;
            g[u] = gl[nbr[e] * EMBED + t];
        }
        // scores: 4 independent shuffle-reduce chains
        float p[4];
#pragma unroll
        for (int u = 0; u < 4; ++u) {
            float x = cg[u] + grv;
            float pv = (x > 0.f ? x : SLOPE * x) * aw;
            pv += __shfl_xor(pv, 1);
            pv += __shfl_xor(pv, 2);
            pv += __shfl_xor(pv, 4);
            pv += __shfl_xor(pv, 8);
            pv += __shfl_xor(pv, 16);
            p[u] = pv;
        }
        // online softmax update (wave-uniform bounds check)
#pragma unroll
        for (int u = 0; u < 4; ++u) {
            if (e0 + u < cnt) {
                float mn = fmaxf(m, p[u]);
                float sc = __expf(m - mn);
                float ev = __expf(p[u] - mn);
                s = s * sc + ev;
                acc = acc * sc + ev * cg[u];
                m = mn;
            }
        }
    }
    out[i * EMBED + t] = acc / s;
}

extern "C" void kernel_launch(void* const* d_in, const int* in_sizes, int n_in,
                              void* d_out, int out_size, void* d_ws, size_t ws_size,
                              hipStream_t stream) {
    const float* h  = (const float*)d_in[0];
    const int*   ei = (const int*)d_in[1];
    const float* Wl = (const float*)d_in[2];
    const float* Wr = (const float*)d_in[3];
    const float* aw = (const float*)d_in[4];
    float* out = (float*)d_out;
    const int E = in_sizes[1] / 2;

    unsigned int* adj = (unsigned int*)d_ws;                 // 128 KB
    float* gl = (float*)((char*)d_ws + 131072);              // 1 MB
    float* gr = gl + NN * EMBED;                             // 1 MB

    k_prep<<<256, 256, 0, stream>>>(h, Wl, Wr, ei, E, gl, gr, adj);
    k_attn<<<NN, 256, 0, stream>>>(gl, gr, adj, aw, out);
}